// Round 3
// baseline (882.295 us; speedup 1.0000x reference)
//
#include <hip/hip_runtime.h>

// FastLoRAEmbedding: out[t,d] = weight[x[t],d] + 16.0 * sum_r a_rows[t,r]*lora_B[d,r]
// x int32 [16384], weight f32 [50257,2048], lora_A f32 [64,50257],
// lora_B f32 [2048,64]. Output f32 [16384, 2048].

constexpr int VOCAB = 50257;
constexpr int DIM = 2048;
constexpr int R = 64;
constexpr float SCALING = 16.0f;   // 128 / sqrt(64)

constexpr int T_TILE = 64;   // tokens per block
constexpr int D_TILE = 64;   // d columns per block (= one wave width)
constexpr int WAVE_T = 16;   // tokens per wave (4 waves, disjoint token sets)
constexpr int BLOCK = 256;

// Stage 1: a_rows[t*R + r] = lora_A[r*VOCAB + x[t]]  (coalesced writes;
// scattered reads hit the L2/L3-resident 12.9 MB lora_A table).
__global__ void gather_a_kernel(const int* __restrict__ x,
                                const float* __restrict__ lora_A,
                                float* __restrict__ a_rows,
                                int n_tokens) {
  int gid = blockIdx.x * blockDim.x + threadIdx.x;
  if (gid >= n_tokens * R) return;
  int t = gid >> 6;          // R == 64
  int r = gid & (R - 1);
  int tok = x[t];
  a_rows[gid] = lora_A[(size_t)r * VOCAB + (size_t)tok];
}

// Stage 2: NO LDS. Wave w of each block owns tokens [t0+w*16, t0+w*16+16),
// lanes <-> 64 d-columns. Token ids and a-row values are wave-uniform ->
// scalar-pipe s_load (free w.r.t. VALU and LDS); inner loop is
// v_fmac_f32 v_acc, s_a, v_b (1 SGPR read per VALU instr: legal).
// weight load / out store are lane<->d contiguous (coalesced 256 B).
__global__ __launch_bounds__(BLOCK) void fused_kernel(
    const int* __restrict__ x,
    const float* __restrict__ weight,
    const float* __restrict__ a_rows,
    const float* __restrict__ lora_B,
    float* __restrict__ out) {
  const int tid = threadIdx.x;
  const int wave = tid >> 6;
  const int lane = tid & 63;
  const int d = blockIdx.y * D_TILE + lane;
  const int t0 = blockIdx.x * T_TILE + wave * WAVE_T;

  // This thread's lora_B row (64 contiguous floats) -> 64 VGPRs, loaded once.
  float b[R];
  {
    const float4* __restrict__ bp =
        reinterpret_cast<const float4*>(lora_B + (size_t)d * R);
#pragma unroll
    for (int i = 0; i < R / 4; ++i) {
      float4 v = bp[i];
      b[4 * i] = v.x; b[4 * i + 1] = v.y; b[4 * i + 2] = v.z; b[4 * i + 3] = v.w;
    }
  }

#pragma unroll 2
  for (int tt = 0; tt < WAVE_T; ++tt) {
    const int t = t0 + tt;
    const int tok = x[t];                          // uniform -> s_load
    const float w = weight[(size_t)tok * DIM + d]; // coalesced vector load

    const float4* __restrict__ ap =
        reinterpret_cast<const float4*>(a_rows + (size_t)t * R);  // uniform
    float a0 = 0.f, a1 = 0.f, a2 = 0.f, a3 = 0.f;
#pragma unroll
    for (int r = 0; r < R / 4; ++r) {
      const float4 av = ap[r];                     // uniform -> s_load_dwordx4
      a0 += av.x * b[4 * r + 0];
      a1 += av.y * b[4 * r + 1];
      a2 += av.z * b[4 * r + 2];
      a3 += av.w * b[4 * r + 3];
    }
    const float acc = (a0 + a1) + (a2 + a3);
    out[(size_t)t * DIM + d] = w + SCALING * acc;  // coalesced store
  }
}

extern "C" void kernel_launch(void* const* d_in, const int* in_sizes, int n_in,
                              void* d_out, int out_size, void* d_ws, size_t ws_size,
                              hipStream_t stream) {
  const int* x = (const int*)d_in[0];
  const float* weight = (const float*)d_in[1];
  const float* lora_A = (const float*)d_in[2];
  const float* lora_B = (const float*)d_in[3];
  float* out = (float*)d_out;

  const int n_tokens = in_sizes[0];               // 16384
  float* a_rows = (float*)d_ws;                   // 4 MB of ws

  const int total = n_tokens * R;
  gather_a_kernel<<<(total + BLOCK - 1) / BLOCK, BLOCK, 0, stream>>>(
      x, lora_A, a_rows, n_tokens);

  dim3 grid(n_tokens / T_TILE, DIM / D_TILE);     // (256, 32) = 8192 blocks
  fused_kernel<<<grid, BLOCK, 0, stream>>>(x, weight, a_rows, lora_B, out);
}

// Round 4
// 607.045 us; speedup vs baseline: 1.4534x; 1.4534x over previous
//
#include <hip/hip_runtime.h>

// FastLoRAEmbedding: out[t,d] = weight[x[t],d] + 16 * sum_r A[r,x[t]] * B[d,r]
// x int32 [16384], weight f32 [50257,2048], lora_A f32 [64,50257],
// lora_B f32 [2048,64]. Output f32 [16384,2048].
//
// Strategy: the rank-64 correction is a [16384x64]x[64x2048] GEMM -> MFMA
// (bf16 inputs; |err| ~1e-3 << 1.2e-1 threshold). Base gather fused into the
// MFMA epilogue so the 134 MB output is written exactly once.

constexpr int VOCAB = 50257;
constexpr int DIM = 2048;
constexpr int R = 64;
constexpr float SCALING = 16.0f;   // 128 / sqrt(64)

typedef short bf16x8 __attribute__((ext_vector_type(8)));  // 8 bf16 = 4 VGPRs
typedef float f32x4 __attribute__((ext_vector_type(4)));

__device__ inline unsigned short f32_to_bf16(float f) {
  unsigned int u = __builtin_bit_cast(unsigned int, f);
  u += 0x7FFFu + ((u >> 16) & 1u);    // round-to-nearest-even (inputs finite)
  return (unsigned short)(u >> 16);
}

// ws layout: [0, 256KB) b_bf16[DIM][R]; [256KB, 256KB+2MB) a_bf16[T][R]
constexpr size_t B_BF16_BYTES = (size_t)DIM * R * sizeof(unsigned short);

// Kernel 1: lora_B fp32 -> bf16, same [d][r] row-major layout.
__global__ void prep_b_kernel(const float* __restrict__ lora_B,
                              unsigned short* __restrict__ b_bf16) {
  int gid = blockIdx.x * blockDim.x + threadIdx.x;   // over DIM*R/4
  const float4 v = reinterpret_cast<const float4*>(lora_B)[gid];
  ushort4 o;
  o.x = f32_to_bf16(v.x); o.y = f32_to_bf16(v.y);
  o.z = f32_to_bf16(v.z); o.w = f32_to_bf16(v.w);
  reinterpret_cast<ushort4*>(b_bf16)[gid] = o;
}

// Kernel 2: a_bf16[t][r] = bf16(lora_A[r*VOCAB + x[t]]).  Thread covers
// (t, 4 consecutive r): 4 scattered reads (12.9 MB table, L2/L3-resident),
// one coalesced 8-B store.
__global__ void gather_a_kernel(const int* __restrict__ x,
                                const float* __restrict__ lora_A,
                                unsigned short* __restrict__ a_bf16,
                                int n_tokens) {
  int gid = blockIdx.x * blockDim.x + threadIdx.x;   // over n_tokens*R/4
  if (gid >= n_tokens * (R / 4)) return;
  int t = gid >> 4;            // 16 quads per token
  int r4 = (gid & 15) * 4;
  int tok = x[t];
  ushort4 o;
  o.x = f32_to_bf16(lora_A[(size_t)(r4 + 0) * VOCAB + tok]);
  o.y = f32_to_bf16(lora_A[(size_t)(r4 + 1) * VOCAB + tok]);
  o.z = f32_to_bf16(lora_A[(size_t)(r4 + 2) * VOCAB + tok]);
  o.w = f32_to_bf16(lora_A[(size_t)(r4 + 3) * VOCAB + tok]);
  reinterpret_cast<ushort4*>(a_bf16)[gid] = o;
}

// Kernel 3: block = 64 tokens x 64 dims, 4 waves; wave w owns tokens
// [tw0, tw0+16) x all 64 dims = 4 MFMA 16x16 tiles, K=64 in two k-halves.
// Frag layouts (gfx950, HW-verified per guide):
//   A[m][k]: m = lane&15, k = (lane>>4)*8 + j      (8 contiguous bf16)
//   B[k][n]: n = lane&15, k = (lane>>4)*8 + j      (8 contiguous bf16)
//   C/D:     col(n) = lane&15, row(m) = (lane>>4)*4 + reg
__global__ __launch_bounds__(256) void fused_mfma_kernel(
    const int* __restrict__ x,
    const float* __restrict__ weight,
    const unsigned short* __restrict__ a_bf16,
    const unsigned short* __restrict__ b_bf16,
    float* __restrict__ out) {
  const int tid = threadIdx.x;
  const int wave = tid >> 6;
  const int lane = tid & 63;
  const int quad = lane >> 4;
  const int l16 = lane & 15;
  const int tw0 = blockIdx.x * 64 + wave * 16;
  const int d0 = blockIdx.y * 64;

  // A fragments (2 k-halves): 16-B loads from the token's contiguous a-row.
  bf16x8 aF[2];
#pragma unroll
  for (int h = 0; h < 2; ++h)
    aF[h] = *reinterpret_cast<const bf16x8*>(
        a_bf16 + (size_t)(tw0 + l16) * R + h * 32 + quad * 8);

  // B fragments (4 d-tiles x 2 k-halves): from the 256 KB L2-resident table.
  bf16x8 bF[4][2];
#pragma unroll
  for (int dt = 0; dt < 4; ++dt)
#pragma unroll
    for (int h = 0; h < 2; ++h)
      bF[dt][h] = *reinterpret_cast<const bf16x8*>(
          b_bf16 + (size_t)(d0 + dt * 16 + l16) * R + h * 32 + quad * 8);

  f32x4 acc[4];
#pragma unroll
  for (int dt = 0; dt < 4; ++dt) {
    acc[dt] = (f32x4){0.f, 0.f, 0.f, 0.f};
#pragma unroll
    for (int h = 0; h < 2; ++h)
      acc[dt] = __builtin_amdgcn_mfma_f32_16x16x32_bf16(
          aF[h], bF[dt][h], acc[dt], 0, 0, 0);
  }

  // Epilogue: row i covers token tw0+quad*4+i; 16 consecutive lanes hit 64 B
  // contiguous weight/out segments (4 segments per instruction).
#pragma unroll
  for (int i = 0; i < 4; ++i) {
    const int t = tw0 + quad * 4 + i;
    const int tok = x[t];
    const float* __restrict__ wrow = weight + (size_t)tok * DIM + d0 + l16;
    float* __restrict__ orow = out + (size_t)t * DIM + d0 + l16;
#pragma unroll
    for (int dt = 0; dt < 4; ++dt)
      orow[dt * 16] = wrow[dt * 16] + SCALING * acc[dt][i];
  }
}

extern "C" void kernel_launch(void* const* d_in, const int* in_sizes, int n_in,
                              void* d_out, int out_size, void* d_ws, size_t ws_size,
                              hipStream_t stream) {
  const int* x = (const int*)d_in[0];
  const float* weight = (const float*)d_in[1];
  const float* lora_A = (const float*)d_in[2];
  const float* lora_B = (const float*)d_in[3];
  float* out = (float*)d_out;

  const int n_tokens = in_sizes[0];               // 16384
  unsigned short* b_bf16 = (unsigned short*)d_ws;
  unsigned short* a_bf16 = (unsigned short*)((char*)d_ws + B_BF16_BYTES);

  prep_b_kernel<<<DIM * R / 4 / 256, 256, 0, stream>>>(lora_B, b_bf16);
  gather_a_kernel<<<(n_tokens * (R / 4) + 255) / 256, 256, 0, stream>>>(
      x, lora_A, a_bf16, n_tokens);

  dim3 grid(n_tokens / 64, DIM / 64);             // (256, 32) = 8192 blocks
  fused_mfma_kernel<<<grid, 256, 0, stream>>>(x, weight, a_bf16, b_bf16, out);
}